// Round 1
// baseline (121.838 us; speedup 1.0000x reference)
//
#include <hip/hip_runtime.h>

#define DIM 256
#define NPIX 4096
#define BS 16

// ---------------- Kernel 1: per-(b,c) spatial sums of rgb and evt ----------
__global__ __launch_bounds__(256) void k_colsum(const float* __restrict__ rgb,
                                                const float* __restrict__ evt,
                                                float* __restrict__ sum_rgb,
                                                float* __restrict__ sum_evt) {
    int bc = blockIdx.x;              // 0 .. BS*DIM-1, one (b,c) row of 4096
    int t  = threadIdx.x;             // 256 threads
    const float4* r4 = (const float4*)(rgb + (size_t)bc * NPIX);
    const float4* e4 = (const float4*)(evt + (size_t)bc * NPIX);
    float sr = 0.f, se = 0.f;
    #pragma unroll
    for (int i = 0; i < 4; ++i) {
        float4 a = r4[t + 256 * i];
        float4 b = e4[t + 256 * i];
        sr += (a.x + a.y) + (a.z + a.w);
        se += (b.x + b.y) + (b.z + b.w);
    }
    // wave(64) reduce
    for (int off = 32; off >= 1; off >>= 1) {
        sr += __shfl_down(sr, off, 64);
        se += __shfl_down(se, off, 64);
    }
    __shared__ float lr[4], le[4];
    int wid = t >> 6, lane = t & 63;
    if (lane == 0) { lr[wid] = sr; le[wid] = se; }
    __syncthreads();
    if (t == 0) {
        sum_rgb[bc] = (lr[0] + lr[1]) + (lr[2] + lr[3]);
        sum_evt[bc] = (le[0] + le[1]) + (le[2] + le[3]);
    }
}

// ---------------- Kernel 2: per-batch k_sum -> v_vec, c ---------------------
__global__ __launch_bounds__(256) void k_vvec(
    const float* __restrict__ sum_rgb, const float* __restrict__ sum_evt,
    const float* __restrict__ Wq_a, const float* __restrict__ bq_a,
    const float* __restrict__ Wk_a, const float* __restrict__ bk_a,
    const float* __restrict__ Wq_d, const float* __restrict__ bq_d,
    const float* __restrict__ Wk_d, const float* __restrict__ bk_d,
    float* __restrict__ va_vec, float* __restrict__ vd_vec,
    float* __restrict__ ca, float* __restrict__ cd) {
    int b = blockIdx.x, t = threadIdx.x;
    __shared__ float s_r[DIM], s_e[DIM], s_ka[DIM], s_kd[DIM];
    s_r[t] = sum_rgb[b * DIM + t];
    s_e[t] = sum_evt[b * DIM + t];
    __syncthreads();
    // k_sum[e] = Wk[e,:] . S + N * bk[e]
    float ka = 0.f, kd = 0.f;
    const float4* wka = (const float4*)(Wk_a + (size_t)t * DIM);
    const float4* wkd = (const float4*)(Wk_d + (size_t)t * DIM);
    #pragma unroll 8
    for (int i = 0; i < DIM / 4; ++i) {
        float4 wa = wka[i], wd = wkd[i];
        ka += wa.x * s_r[4*i] + wa.y * s_r[4*i+1] + wa.z * s_r[4*i+2] + wa.w * s_r[4*i+3];
        kd += wd.x * s_e[4*i] + wd.y * s_e[4*i+1] + wd.z * s_e[4*i+2] + wd.w * s_e[4*i+3];
    }
    s_ka[t] = ka + 4096.0f * bk_a[t];
    s_kd[t] = kd + 4096.0f * bk_d[t];
    __syncthreads();
    // v_vec[d] = sum_e Wq[e,d] * k_sum[e]   (coalesced column access)
    float va = 0.f, vd = 0.f;
    #pragma unroll 8
    for (int e = 0; e < DIM; ++e) {
        va += Wq_a[(size_t)e * DIM + t] * s_ka[e];
        vd += Wq_d[(size_t)e * DIM + t] * s_kd[e];
    }
    va_vec[b * DIM + t] = va;
    vd_vec[b * DIM + t] = vd;
    // c = bq . k_sum  (block reduce)
    float pa = bq_a[t] * s_ka[t];
    float pd = bq_d[t] * s_kd[t];
    for (int off = 32; off >= 1; off >>= 1) {
        pa += __shfl_down(pa, off, 64);
        pd += __shfl_down(pd, off, 64);
    }
    __shared__ float ra[4], rd[4];
    int wid = t >> 6, lane = t & 63;
    if (lane == 0) { ra[wid] = pa; rd[wid] = pd; }
    __syncthreads();
    if (t == 0) {
        ca[b] = (ra[0] + ra[1]) + (ra[2] + ra[3]);
        cd[b] = (rd[0] + rd[1]) + (rd[2] + rd[3]);
    }
}

// ---------------- Kernel 3: per-pixel dot, softmax, blend -------------------
__global__ __launch_bounds__(256) void k_fuse(
    const float* __restrict__ rgb, const float* __restrict__ evt,
    const float* __restrict__ va_vec, const float* __restrict__ vd_vec,
    const float* __restrict__ ca, const float* __restrict__ cd,
    float* __restrict__ out) {
    int b = blockIdx.y;
    int t = threadIdx.x;
    int n = blockIdx.x * 256 + t;     // pixel index 0..4095
    __shared__ float s_va[DIM], s_vd[DIM];
    s_va[t] = va_vec[b * DIM + t];
    s_vd[t] = vd_vec[b * DIM + t];
    __syncthreads();
    const float* rb = rgb + (size_t)b * DIM * NPIX;
    const float* eb = evt + (size_t)b * DIM * NPIX;
    float acc_a = 0.f, acc_d = 0.f;
    #pragma unroll 8
    for (int c = 0; c < DIM; ++c) {
        acc_a += rb[(size_t)c * NPIX + n] * s_va[c];
        acc_d += eb[(size_t)c * NPIX + n] * s_vd[c];
    }
    float va = (acc_a + ca[b]) * 0.0625f;   // 1/sqrt(256)
    float vd = (acc_d + cd[b]) * 0.0625f;
    float m  = fmaxf(va, vd);
    float ea = expf(va - m), ed = expf(vd - m);
    float inv = 1.0f / (ea + ed);
    float wa = ea * inv, wd = ed * inv;
    float* ob = out + (size_t)b * DIM * NPIX;
    #pragma unroll 8
    for (int c = 0; c < DIM; ++c) {
        float x = rb[(size_t)c * NPIX + n];
        float y = eb[(size_t)c * NPIX + n];
        ob[(size_t)c * NPIX + n] = wa * x + wd * y;
    }
}

extern "C" void kernel_launch(void* const* d_in, const int* in_sizes, int n_in,
                              void* d_out, int out_size, void* d_ws, size_t ws_size,
                              hipStream_t stream) {
    const float* rgb  = (const float*)d_in[0];
    const float* evt  = (const float*)d_in[1];
    const float* Wq_a = (const float*)d_in[2];
    const float* bq_a = (const float*)d_in[3];
    const float* Wk_a = (const float*)d_in[4];
    const float* bk_a = (const float*)d_in[5];
    const float* Wq_d = (const float*)d_in[6];
    const float* bq_d = (const float*)d_in[7];
    const float* Wk_d = (const float*)d_in[8];
    const float* bk_d = (const float*)d_in[9];
    float* out = (float*)d_out;

    float* ws      = (float*)d_ws;
    float* sum_rgb = ws;                 // BS*DIM
    float* sum_evt = ws + BS * DIM;      // BS*DIM
    float* va_vec  = ws + 2 * BS * DIM;  // BS*DIM
    float* vd_vec  = ws + 3 * BS * DIM;  // BS*DIM
    float* ca      = ws + 4 * BS * DIM;  // BS
    float* cd      = ws + 4 * BS * DIM + BS;

    k_colsum<<<BS * DIM, 256, 0, stream>>>(rgb, evt, sum_rgb, sum_evt);
    k_vvec<<<BS, 256, 0, stream>>>(sum_rgb, sum_evt,
                                   Wq_a, bq_a, Wk_a, bk_a,
                                   Wq_d, bq_d, Wk_d, bk_d,
                                   va_vec, vd_vec, ca, cd);
    dim3 g3(NPIX / 256, BS);
    k_fuse<<<g3, 256, 0, stream>>>(rgb, evt, va_vec, vd_vec, ca, cd, out);
}

// Round 2
// 102.531 us; speedup vs baseline: 1.1883x; 1.1883x over previous
//
#include <hip/hip_runtime.h>

#define DIM 256
#define NPIX 4096
#define BS 16

// Workspace layout (floats):
//   sum_rgb : [0]       4096   (b*256+c spatial sums of rgb)
//   sum_evt : [4096]    4096
//   MT      : [8192]    2*65536  MT[m][d*256+i] = M_m[i,d] = sum_e Wq[e,i]Wk[e,d]
//   u       : [139264]  2*256    u_m[i] = N * sum_e Wq[e,i] bk[e]
//   wv      : [139776]  2*256    w_m[d] = sum_e Wk[e,d] bq[e]
//   s0      : [140288]  2        s0_m  = N * (bq . bk)
//   v       : [140292]  2*16*256 v_{m,b}[i]
//   cc      : [148484]  2*16     c_{m,b}
#define WS_SUMR 0
#define WS_SUME 4096
#define WS_MT   8192
#define WS_U    139264
#define WS_WV   139776
#define WS_S0   140288
#define WS_V    140292
#define WS_C    148484

// ---- Phase 1: spatial column sums (blocks 0..1023) + weight precompute
//      (blocks 1024..1535) fused into one grid so they overlap.
__global__ __launch_bounds__(256) void k_phase1(
    const float* __restrict__ rgb, const float* __restrict__ evt,
    const float* __restrict__ Wq_a, const float* __restrict__ bq_a,
    const float* __restrict__ Wk_a, const float* __restrict__ bk_a,
    const float* __restrict__ Wq_d, const float* __restrict__ bq_d,
    const float* __restrict__ Wk_d, const float* __restrict__ bk_d,
    float* __restrict__ ws) {
    int t = threadIdx.x;
    if (blockIdx.x < 1024) {
        // one wave per (b,c) row of both arrays; 16 float4 per lane per array
        int wid = t >> 6, lane = t & 63;
        int bc = blockIdx.x * 4 + wid;
        const float4* r4 = (const float4*)(rgb + (size_t)bc * NPIX);
        const float4* e4 = (const float4*)(evt + (size_t)bc * NPIX);
        float sr = 0.f, se = 0.f;
        #pragma unroll
        for (int i = 0; i < 16; ++i) {
            float4 a = r4[lane + 64 * i];
            float4 b = e4[lane + 64 * i];
            sr += (a.x + a.y) + (a.z + a.w);
            se += (b.x + b.y) + (b.z + b.w);
        }
        #pragma unroll
        for (int off = 32; off >= 1; off >>= 1) {
            sr += __shfl_down(sr, off, 64);
            se += __shfl_down(se, off, 64);
        }
        if (lane == 0) { ws[WS_SUMR + bc] = sr; ws[WS_SUME + bc] = se; }
    } else {
        int pid = blockIdx.x - 1024;
        int d = pid & 255, m = pid >> 8;
        const float* Wq = m ? Wq_d : Wq_a;
        const float* Wk = m ? Wk_d : Wk_a;
        const float* bq = m ? bq_d : bq_a;
        const float* bk = m ? bk_d : bk_a;
        int i = t;
        // MT[m][d*256+i] = sum_e Wq[e,i] * Wk[e,d]   (Wk[e,d] block-uniform -> s_load)
        float acc = 0.f;
        #pragma unroll 8
        for (int e = 0; e < 256; ++e)
            acc += Wq[e * 256 + i] * Wk[e * 256 + d];
        ws[WS_MT + m * 65536 + d * 256 + i] = acc;
        // wv[m][d] = sum_e Wk[e,d]*bq[e]  (block reduce; Wk rows L2-hot now)
        float p = Wk[i * 256 + d] * bq[i];
        #pragma unroll
        for (int off = 32; off >= 1; off >>= 1) p += __shfl_down(p, off, 64);
        __shared__ float red[4];
        if ((t & 63) == 0) red[t >> 6] = p;
        __syncthreads();
        if (t == 0) ws[WS_WV + m * 256 + d] = (red[0] + red[1]) + (red[2] + red[3]);
        if (d == 0) {
            float ua = 0.f;
            #pragma unroll 8
            for (int e = 0; e < 256; ++e)
                ua += Wq[e * 256 + i] * bk[e];
            ws[WS_U + m * 256 + i] = 4096.0f * ua;
            float q = bq[i] * bk[i];
            #pragma unroll
            for (int off = 32; off >= 1; off >>= 1) q += __shfl_down(q, off, 64);
            __shared__ float red2[4];
            if ((t & 63) == 0) red2[t >> 6] = q;
            __syncthreads();
            if (t == 0) ws[WS_S0 + m] = 4096.0f * ((red2[0] + red2[1]) + (red2[2] + red2[3]));
        }
    }
}

// ---- Phase 2: per (b,branch) matvec over L2-hot MT: v = M S + u, c = w.S + s0
__global__ __launch_bounds__(256) void k_vvec2(float* __restrict__ ws) {
    int b = blockIdx.x, m = blockIdx.y;
    int i = threadIdx.x;
    const float* S = ws + (m ? WS_SUME : WS_SUMR) + b * 256;
    __shared__ float sS[256];
    sS[i] = S[i];
    __syncthreads();
    float acc = ws[WS_U + m * 256 + i];
    const float* Mp = ws + WS_MT + m * 65536;
    #pragma unroll 8
    for (int d = 0; d < 256; ++d)
        acc += Mp[d * 256 + i] * sS[d];
    ws[WS_V + (m * BS + b) * 256 + i] = acc;
    float p = ws[WS_WV + m * 256 + i] * sS[i];
    #pragma unroll
    for (int off = 32; off >= 1; off >>= 1) p += __shfl_down(p, off, 64);
    __shared__ float red[4];
    if ((i & 63) == 0) red[i >> 6] = p;
    __syncthreads();
    if (i == 0) ws[WS_C + m * BS + b] =
        (red[0] + red[1]) + (red[2] + red[3]) + ws[WS_S0 + m];
}

// ---- Phase 3: per-pixel dot / softmax / blend.
// Grid (64, 16): 64-pixel tiles, wave w owns channels [64w, 64w+64).
__global__ __launch_bounds__(256) void k_fuse(
    const float* __restrict__ rgb, const float* __restrict__ evt,
    const float* __restrict__ ws, float* __restrict__ out) {
    int b = blockIdx.y;
    int t = threadIdx.x;
    int wid = t >> 6, lane = t & 63;
    int n = blockIdx.x * 64 + lane;
    int c0 = wid * 64;
    __shared__ float s_va[DIM], s_vd[DIM];
    s_va[t] = ws[WS_V + b * 256 + t];
    s_vd[t] = ws[WS_V + (BS + b) * 256 + t];
    __syncthreads();
    const float* rb = rgb + (size_t)b * DIM * NPIX + n;
    const float* eb = evt + (size_t)b * DIM * NPIX + n;
    float acc_a = 0.f, acc_d = 0.f;
    #pragma unroll 8
    for (int c = 0; c < 64; ++c) {
        acc_a += rb[(size_t)(c0 + c) * NPIX] * s_va[c0 + c];
        acc_d += eb[(size_t)(c0 + c) * NPIX] * s_vd[c0 + c];
    }
    __shared__ float s_pa[4][64], s_pd[4][64];
    s_pa[wid][lane] = acc_a; s_pd[wid][lane] = acc_d;
    __syncthreads();
    float va = (s_pa[0][lane] + s_pa[1][lane] + s_pa[2][lane] + s_pa[3][lane]
                + ws[WS_C + b]) * 0.0625f;
    float vd = (s_pd[0][lane] + s_pd[1][lane] + s_pd[2][lane] + s_pd[3][lane]
                + ws[WS_C + BS + b]) * 0.0625f;
    float mm = fmaxf(va, vd);
    float ea = expf(va - mm), ed = expf(vd - mm);
    float inv = 1.0f / (ea + ed);
    float wa = ea * inv, wd = ed * inv;
    float* ob = out + (size_t)b * DIM * NPIX + n;
    #pragma unroll 8
    for (int c = 0; c < 64; ++c) {
        float x = rb[(size_t)(c0 + c) * NPIX];
        float y = eb[(size_t)(c0 + c) * NPIX];
        ob[(size_t)(c0 + c) * NPIX] = wa * x + wd * y;
    }
}

extern "C" void kernel_launch(void* const* d_in, const int* in_sizes, int n_in,
                              void* d_out, int out_size, void* d_ws, size_t ws_size,
                              hipStream_t stream) {
    const float* rgb  = (const float*)d_in[0];
    const float* evt  = (const float*)d_in[1];
    const float* Wq_a = (const float*)d_in[2];
    const float* bq_a = (const float*)d_in[3];
    const float* Wk_a = (const float*)d_in[4];
    const float* bk_a = (const float*)d_in[5];
    const float* Wq_d = (const float*)d_in[6];
    const float* bq_d = (const float*)d_in[7];
    const float* Wk_d = (const float*)d_in[8];
    const float* bk_d = (const float*)d_in[9];
    float* out = (float*)d_out;
    float* ws  = (float*)d_ws;

    k_phase1<<<1536, 256, 0, stream>>>(rgb, evt,
                                       Wq_a, bq_a, Wk_a, bk_a,
                                       Wq_d, bq_d, Wk_d, bk_d, ws);
    dim3 g2(BS, 2);
    k_vvec2<<<g2, 256, 0, stream>>>(ws);
    dim3 g3(NPIX / 64, BS);
    k_fuse<<<g3, 256, 0, stream>>>(rgb, evt, ws, out);
}